// Round 9
// baseline (143.850 us; speedup 1.0000x reference)
//
#include <hip/hip_runtime.h>
#include <hip/hip_bf16.h>

// out[n] = sum_m coefs[m] * exp(-||L_m^T (x_n - c_m)||^2),  coefs[m]=softmax(w)[m]*|det L_m|
// N=131072, M=32, D=32, f32.
//
// Round 8 (resubmit after GPUAcquisitionTimeout): latency-attack restructure.
// Evidence: epilogue halving (r3) and LDS staging (r7) both ~null -> gmm_main
// (~40us, <=42.2 by top-5 bound) is LATENCY-bound at 4 waves/SIMD with 4096
// waves (no TLP reserve), not throughput-bound. New structure:
//  - 4 m-groups x 8 centers; block = 256 thr (4 waves), WT=4 (64 pts/wave)
//  - grid 2048 blocks = 8192 waves = 2x oversubscription -> wave rotation hides
//    the per-m chain (MFMA x3 -> DPP reduce -> exp2)
//  - NO LDS; B-frags per-m from L2-hot 144 KB table (unroll-2 hoists loads)
//  - groups write disjoint parts[g][n]; tiny reduce kernel sums 4/point
//    (deterministic, no atomics, no memset)

#define D 32
#define M 32
#define WT 4      // point-tiles (of 16) per wave
#define GROUPS 4
#define MPG 8     // centers per group

typedef __attribute__((ext_vector_type(8))) short short8;
typedef __attribute__((ext_vector_type(4))) float f32x4;

__device__ __forceinline__ unsigned short f2bf_rne(float f) {
  unsigned int u = __float_as_uint(f);
  return (unsigned short)((u + 0x7FFFu + ((u >> 16) & 1u)) >> 16);
}

// x + dpp(x); 0x128=row_ror:8 0x124=row_ror:4 (coset sums), 0xB1/0x4E quad_perm
#define DPP_ADD(x, ctrl) \
  ((x) + __int_as_float(__builtin_amdgcn_mov_dpp(__float_as_int(x), (ctrl), 0xf, 0xf, true)))

#define SCL 1.2011224087864498f  // sqrt(log2(e))

__global__ __launch_bounds__(64) void gmm_pre(
    const float* __restrict__ centers, const float* __restrict__ L,
    const float* __restrict__ weights,
    float2* __restrict__ CNp, float* __restrict__ LC,
    unsigned short* __restrict__ LH, unsigned short* __restrict__ LL) {
  __shared__ float U[D][D + 1];
  __shared__ float C2s[D];
  const int m = blockIdx.x;
  const int t = threadIdx.x;
  const float* Lm = L + m * (D * D);

  if (t < D) {
    for (int k = 0; k < D; ++k) U[t][k] = Lm[t * D + k];
    float acc = 0.f;
    for (int d = 0; d < D; ++d) acc = fmaf(centers[m * D + d], Lm[d * D + t], acc);
    C2s[t] = acc;  // (L^T c)_t, unscaled
  }

  // B-fragment split of (SCL * L), layout [m][ktile][lane][j]
  {
    const int col = t & 15;
    const int dbase = 8 * (t >> 4);
    for (int kt = 0; kt < 2; ++kt) {
      for (int j = 0; j < 8; ++j) {
        const int d = dbase + j;
        const int k = kt * 16 + col;
        float v = Lm[d * D + k] * SCL;
        unsigned int hi = __float_as_uint(v) & 0xFFFF0000u;
        float lo = v - __uint_as_float(hi);
        size_t off = (((size_t)(m * 2 + kt)) * 64 + t) * 8 + j;
        LH[off] = (unsigned short)(hi >> 16);
        LL[off] = f2bf_rne(lo);
      }
    }
  }
  __syncthreads();

  // bias pair table: CNp[m][col] = (-(sL)^T c [col], -(sL)^T c [col+16])
  if (t < 16) CNp[m * 16 + t] = make_float2(-SCL * C2s[t], -SCL * C2s[16 + t]);

  // LU (no pivot; L ~ I + 0.05*noise) for |det|
  for (int p = 0; p < D - 1; ++p) {
    if (t > p && t < D) {
      float f = U[t][p] / U[p][p];
      for (int k = p; k < D; ++k) U[t][k] -= f * U[p][k];
    }
    __syncthreads();
  }
  if (t == 0) {
    float det = 1.f;
    for (int i = 0; i < D; ++i) det *= U[i][i];
    float mx = -1e30f;
    for (int j = 0; j < M; ++j) mx = fmaxf(mx, weights[j]);
    float s = 0.f;
    for (int j = 0; j < M; ++j) s += __expf(weights[j] - mx);
    float coef = (__expf(weights[m] - mx) / s) * fabsf(det);
    LC[m] = log2f(coef);
  }
}

__global__ __launch_bounds__(256, 4) void gmm_main(
    const float* __restrict__ points,
    const float2* __restrict__ CNp, const float* __restrict__ LC,
    const unsigned short* __restrict__ LH, const unsigned short* __restrict__ LL,
    float* __restrict__ parts, int N) {
  const int pblocks = N >> 8;  // 256 points per block
  const int group = blockIdx.x / pblocks;
  const int pblk = blockIdx.x - group * pblocks;
  const int m0 = group * MPG;

  const int lane = threadIdx.x & 63;
  const int wave = threadIdx.x >> 6;  // 0..3
  const int col = lane & 15;          // A-row (point) / B-col (k)
  const int g = lane >> 4;            // A k-slot base 8g; D rows 4g..4g+3
  const int tileBase = (pblk * 4 + wave) * (WT * 16);

  // lane-transpose selectors: lane i keeps coset i&3, picks r=(i>>2)&3
  const bool b0 = (lane >> 2) & 1;
  const bool b1 = (lane >> 2) & 2;

  // ---- load X tiles, Dekker-split into bf16 hi/lo fragments ----
  short8 xh[WT], xl[WT];
#pragma unroll
  for (int t = 0; t < WT; ++t) {
    const float* p = points + (size_t)(tileBase + t * 16 + col) * D + 8 * g;
    float4 a = *reinterpret_cast<const float4*>(p);
    float4 b = *reinterpret_cast<const float4*>(p + 4);
    float v[8] = {a.x, a.y, a.z, a.w, b.x, b.y, b.z, b.w};
    unsigned int hiu[8];
    unsigned int lou[8];
#pragma unroll
    for (int j = 0; j < 8; ++j) {
      unsigned int u = __float_as_uint(v[j]);
      hiu[j] = u & 0xFFFF0000u;  // exact split
      lou[j] = __float_as_uint(v[j] - __uint_as_float(hiu[j]));
    }
    union { short8 s; unsigned int w[4]; } H, Lo;
#pragma unroll
    for (int jj = 0; jj < 4; ++jj) {
      H.w[jj]  = __builtin_amdgcn_perm(hiu[2 * jj + 1], hiu[2 * jj], 0x07060302);
      Lo.w[jj] = __builtin_amdgcn_perm(lou[2 * jj + 1], lou[2 * jj], 0x07060302);
    }
    xh[t] = H.s;
    xl[t] = Lo.s;
  }

  float result[WT];
#pragma unroll
  for (int t = 0; t < WT; ++t) result[t] = 0.f;

  const short8* bh_base = reinterpret_cast<const short8*>(LH);
  const short8* bl_base = reinterpret_cast<const short8*>(LL);

#pragma unroll 2
  for (int mi = 0; mi < MPG; ++mi) {
    const int m = m0 + mi;
    short8 bh0 = bh_base[(m * 2 + 0) * 64 + lane];  // L2-hot (144 KB table/XCD)
    short8 bh1 = bh_base[(m * 2 + 1) * 64 + lane];
    short8 bl0 = bl_base[(m * 2 + 0) * 64 + lane];
    short8 bl1 = bl_base[(m * 2 + 1) * 64 + lane];
    const float2 cn = CNp[m * 16 + col];
    const float lc = LC[m];  // wave-uniform -> s_load

#pragma unroll
    for (int t = 0; t < WT; ++t) {
      f32x4 acc0 = (f32x4){cn.x, cn.x, cn.x, cn.x};  // z = (sL)^T x - (sL)^T c
      f32x4 acc1 = (f32x4){cn.y, cn.y, cn.y, cn.y};
      acc0 = __builtin_amdgcn_mfma_f32_16x16x32_bf16(xh[t], bh0, acc0, 0, 0, 0);
      acc0 = __builtin_amdgcn_mfma_f32_16x16x32_bf16(xl[t], bh0, acc0, 0, 0, 0);
      acc0 = __builtin_amdgcn_mfma_f32_16x16x32_bf16(xh[t], bl0, acc0, 0, 0, 0);
      acc1 = __builtin_amdgcn_mfma_f32_16x16x32_bf16(xh[t], bh1, acc1, 0, 0, 0);
      acc1 = __builtin_amdgcn_mfma_f32_16x16x32_bf16(xl[t], bh1, acc1, 0, 0, 0);
      acc1 = __builtin_amdgcn_mfma_f32_16x16x32_bf16(xh[t], bl1, acc1, 0, 0, 0);

      // coset partials: 2 ror-adds per r
      float s0 = fmaf(acc0[0], acc0[0], acc1[0] * acc1[0]);
      float s1 = fmaf(acc0[1], acc0[1], acc1[1] * acc1[1]);
      float s2 = fmaf(acc0[2], acc0[2], acc1[2] * acc1[2]);
      float s3 = fmaf(acc0[3], acc0[3], acc1[3] * acc1[3]);
      s0 = DPP_ADD(s0, 0x128); s0 = DPP_ADD(s0, 0x124);
      s1 = DPP_ADD(s1, 0x128); s1 = DPP_ADD(s1, 0x124);
      s2 = DPP_ADD(s2, 0x128); s2 = DPP_ADD(s2, 0x124);
      s3 = DPP_ADD(s3, 0x128); s3 = DPP_ADD(s3, 0x124);
      // lane-transpose + quad butterfly -> full dist per quad
      float v = b1 ? (b0 ? s3 : s2) : (b0 ? s1 : s0);
      v = DPP_ADD(v, 0xB1);
      v = DPP_ADD(v, 0x4E);
      result[t] += exp2f(lc - v);  // coef*exp(-dist) = 2^(lc - dist_log2)
    }
  }

  // lane 16g+4q (q=(lane>>2)&3, lane&3==0) holds result for point t*16+4g+q
  if ((lane & 3) == 0) {
    const int q = (lane >> 2) & 3;
    float* dst = parts + (size_t)group * N + tileBase;
#pragma unroll
    for (int t = 0; t < WT; ++t)
      dst[t * 16 + 4 * g + q] = result[t];
  }
}

__global__ __launch_bounds__(256) void gmm_reduce(
    const float* __restrict__ parts, float* __restrict__ out, int N) {
  const int n = blockIdx.x * 256 + threadIdx.x;
  if (n < N) {
    float s = (parts[n] + parts[(size_t)N + n]) +
              (parts[2 * (size_t)N + n] + parts[3 * (size_t)N + n]);
    out[n] = s;
  }
}

extern "C" void kernel_launch(void* const* d_in, const int* in_sizes, int n_in,
                              void* d_out, int out_size, void* d_ws, size_t ws_size,
                              hipStream_t stream) {
  const float* points  = (const float*)d_in[0];
  const float* centers = (const float*)d_in[1];
  const float* L       = (const float*)d_in[2];
  const float* weights = (const float*)d_in[3];
  float* out = (float*)d_out;
  const int N = in_sizes[0] / D;

  char* ws = (char*)d_ws;
  float2* CNp         = (float2*)ws;                    // 4096 B
  float* LC           = (float*)(ws + 4096);            // 128 B
  unsigned short* LHf = (unsigned short*)(ws + 8192);   // 65536 B
  unsigned short* LLf = (unsigned short*)(ws + 8192 + 65536);
  float* parts        = (float*)(ws + 262144);          // GROUPS*N*4 = 2 MB

  gmm_pre<<<M, 64, 0, stream>>>(centers, L, weights, CNp, LC, LHf, LLf);

  const int pblocks = N >> 8;  // 256 pts per block (4 waves x 64)
  gmm_main<<<GROUPS * pblocks, 256, 0, stream>>>(
      points, CNp, LC, LHf, LLf, parts, N);

  gmm_reduce<<<(N + 255) / 256, 256, 0, stream>>>(parts, out, N);
}

// Round 12
// 114.055 us; speedup vs baseline: 1.2612x; 1.2612x over previous
//
#include <hip/hip_runtime.h>
#include <hip/hip_bf16.h>

// out[n] = sum_m coefs[m] * exp(-||L_m^T (x_n - c_m)||^2),  coefs[m]=softmax(w)[m]*|det L_m|
// N=131072, M=32, D=32, f32.
//
// Round 11 (resubmit after GPUAcquisitionTimeout): BISECT of r10's post-timing
// divergence. Base = r7 shell (two kernels, 1024-thr block, 132 KB LDS tables,
// per-m in-loop table reads, unroll 2 — passed post-timing 4x). Applied ONLY
// r10's swapped-operand MFMA + shfl epilogue:
//   acc = mfma(A=L-frag, B=x-frag) -> D[row=k][col=point]; k-reduce = 8 in-lane
//   squares + shfl_xor(16) + shfl_xor(32). No software pipeline, no prefetch
//   register rotation (r10's other novelty, suspected in the divergence).

#define D 32
#define M 32
#define WT 2  // point-tiles (of 16) per wave

typedef __attribute__((ext_vector_type(8))) short short8;
typedef __attribute__((ext_vector_type(4))) float f32x4;

__device__ __forceinline__ unsigned short f2bf_rne(float f) {
  unsigned int u = __float_as_uint(f);
  return (unsigned short)((u + 0x7FFFu + ((u >> 16) & 1u)) >> 16);
}

#define SCL 1.2011224087864498f  // sqrt(log2(e))

__global__ __launch_bounds__(64) void gmm_pre(
    const float* __restrict__ centers, const float* __restrict__ L,
    const float* __restrict__ weights,
    float* __restrict__ CNf, float* __restrict__ LC,
    unsigned short* __restrict__ LH, unsigned short* __restrict__ LL) {
  __shared__ float U[D][D + 1];
  __shared__ float C2s[D];
  const int m = blockIdx.x;
  const int t = threadIdx.x;
  const float* Lm = L + m * (D * D);

  if (t < D) {
    for (int k = 0; k < D; ++k) U[t][k] = Lm[t * D + k];
    float acc = 0.f;
    for (int d = 0; d < D; ++d) acc = fmaf(centers[m * D + d], Lm[d * D + t], acc);
    C2s[t] = acc;  // (L^T c)_t, unscaled
  }

  // B-fragment split of (SCL * L), layout [m][ktile][lane][j]
  // content: lane&15 = k index, d-slot = 8*(lane>>4)+j  (same as rounds 2-9)
  {
    const int col = t & 15;
    const int dbase = 8 * (t >> 4);
    for (int kt = 0; kt < 2; ++kt) {
      for (int j = 0; j < 8; ++j) {
        const int d = dbase + j;
        const int k = kt * 16 + col;
        float v = Lm[d * D + k] * SCL;
        unsigned int hi = __float_as_uint(v) & 0xFFFF0000u;
        float lo = v - __uint_as_float(hi);
        size_t off = (((size_t)(m * 2 + kt)) * 64 + t) * 8 + j;
        LH[off] = (unsigned short)(hi >> 16);
        LL[off] = f2bf_rne(lo);
      }
    }
  }
  __syncthreads();

  // bias in k-natural order: CNf[m][k] = -(sL^T c)_k
  if (t < D) CNf[m * D + t] = -SCL * C2s[t];

  // LU (no pivot; L ~ I + 0.05*noise) for |det|
  for (int p = 0; p < D - 1; ++p) {
    if (t > p && t < D) {
      float f = U[t][p] / U[p][p];
      for (int k = p; k < D; ++k) U[t][k] -= f * U[p][k];
    }
    __syncthreads();
  }
  if (t == 0) {
    float det = 1.f;
    for (int i = 0; i < D; ++i) det *= U[i][i];
    float mx = -1e30f;
    for (int j = 0; j < M; ++j) mx = fmaxf(mx, weights[j]);
    float s = 0.f;
    for (int j = 0; j < M; ++j) s += __expf(weights[j] - mx);
    float coef = (__expf(weights[m] - mx) / s) * fabsf(det);
    LC[m] = log2f(coef);
  }
}

__global__ __launch_bounds__(1024, 4) void gmm_main(
    const float* __restrict__ points,
    const float* __restrict__ CNf, const float* __restrict__ LC,
    const unsigned short* __restrict__ LH, const unsigned short* __restrict__ LL,
    float* __restrict__ out, int N) {
  // 132 KB LDS: whole fragment + bias tables resident per CU
  __shared__ unsigned short sLH[M * 2 * 64 * 8];  // 64 KB
  __shared__ unsigned short sLL[M * 2 * 64 * 8];  // 64 KB
  __shared__ float sCNf[M * D];                   // 4 KB

  const int tid = threadIdx.x;
  const int lane = tid & 63;
  const int wave = tid >> 6;  // 0..15
  const int col = lane & 15;  // x-frag: point; L-frag: k
  const int g = lane >> 4;    // d-slot base 8g; D rows k = 4g+reg (+16 per k-tile)

  // ---- one-time stage: 128 KB fragments + 4 KB bias into LDS ----
  {
    const uint4* src = reinterpret_cast<const uint4*>(LH);
    uint4* dst = reinterpret_cast<uint4*>(sLH);
#pragma unroll
    for (int i = 0; i < 4; ++i) dst[tid + i * 1024] = src[tid + i * 1024];
    src = reinterpret_cast<const uint4*>(LL);
    dst = reinterpret_cast<uint4*>(sLL);
#pragma unroll
    for (int i = 0; i < 4; ++i) dst[tid + i * 1024] = src[tid + i * 1024];
    if (tid < M * D / 4) {
      reinterpret_cast<float4*>(sCNf)[tid] =
          reinterpret_cast<const float4*>(CNf)[tid];
    }
  }

  const int tileBase = (blockIdx.x * 16 + wave) * (WT * 16);

  // ---- load X tiles, Dekker-split into bf16 hi/lo fragments (B-operand) ----
  short8 xh0, xl0, xh1, xl1;
#pragma unroll
  for (int t = 0; t < WT; ++t) {
    const float* p = points + (size_t)(tileBase + t * 16 + col) * D + 8 * g;
    float4 a = *reinterpret_cast<const float4*>(p);
    float4 b = *reinterpret_cast<const float4*>(p + 4);
    float v[8] = {a.x, a.y, a.z, a.w, b.x, b.y, b.z, b.w};
    unsigned int hiu[8];
    unsigned int lou[8];
#pragma unroll
    for (int j = 0; j < 8; ++j) {
      unsigned int u = __float_as_uint(v[j]);
      hiu[j] = u & 0xFFFF0000u;  // exact split
      lou[j] = __float_as_uint(v[j] - __uint_as_float(hiu[j]));
    }
    union { short8 s; unsigned int w[4]; } H, Lo;
#pragma unroll
    for (int jj = 0; jj < 4; ++jj) {
      H.w[jj]  = __builtin_amdgcn_perm(hiu[2 * jj + 1], hiu[2 * jj], 0x07060302);
      Lo.w[jj] = __builtin_amdgcn_perm(lou[2 * jj + 1], lou[2 * jj], 0x07060302);
    }
    if (t == 0) { xh0 = H.s; xl0 = Lo.s; } else { xh1 = H.s; xl1 = Lo.s; }
  }

  __syncthreads();  // LDS tables ready

  float result0 = 0.f, result1 = 0.f;

  const short8* bh_base = reinterpret_cast<const short8*>(sLH);
  const short8* bl_base = reinterpret_cast<const short8*>(sLL);
  const float4* cn_base = reinterpret_cast<const float4*>(sCNf);

#pragma unroll 2
  for (int m = 0; m < M; ++m) {
    short8 bh0 = bh_base[(m * 2 + 0) * 64 + lane];  // ds_read_b128, conflict-free
    short8 bh1 = bh_base[(m * 2 + 1) * 64 + lane];
    short8 bl0 = bl_base[(m * 2 + 0) * 64 + lane];
    short8 bl1 = bl_base[(m * 2 + 1) * 64 + lane];
    float4 cn0 = cn_base[m * 8 + g];      // bias k = 4g..4g+3
    float4 cn1 = cn_base[m * 8 + 4 + g];  // bias k = 16+4g..16+4g+3
    const float lc = LC[m];               // wave-uniform -> s_load

    // z = (sL)^T x - (sL)^T c : D[row=k][col=point]
    f32x4 a00 = (f32x4){cn0.x, cn0.y, cn0.z, cn0.w};  // t=0, k-tile 0
    f32x4 a01 = (f32x4){cn1.x, cn1.y, cn1.z, cn1.w};  // t=0, k-tile 1
    f32x4 a10 = a00;                                  // t=1 same bias
    f32x4 a11 = a01;
    a00 = __builtin_amdgcn_mfma_f32_16x16x32_bf16(bh0, xh0, a00, 0, 0, 0);
    a01 = __builtin_amdgcn_mfma_f32_16x16x32_bf16(bh1, xh0, a01, 0, 0, 0);
    a10 = __builtin_amdgcn_mfma_f32_16x16x32_bf16(bh0, xh1, a10, 0, 0, 0);
    a11 = __builtin_amdgcn_mfma_f32_16x16x32_bf16(bh1, xh1, a11, 0, 0, 0);
    a00 = __builtin_amdgcn_mfma_f32_16x16x32_bf16(bl0, xh0, a00, 0, 0, 0);
    a01 = __builtin_amdgcn_mfma_f32_16x16x32_bf16(bl1, xh0, a01, 0, 0, 0);
    a10 = __builtin_amdgcn_mfma_f32_16x16x32_bf16(bl0, xh1, a10, 0, 0, 0);
    a11 = __builtin_amdgcn_mfma_f32_16x16x32_bf16(bl1, xh1, a11, 0, 0, 0);
    a00 = __builtin_amdgcn_mfma_f32_16x16x32_bf16(bh0, xl0, a00, 0, 0, 0);
    a01 = __builtin_amdgcn_mfma_f32_16x16x32_bf16(bh1, xl0, a01, 0, 0, 0);
    a10 = __builtin_amdgcn_mfma_f32_16x16x32_bf16(bh0, xl1, a10, 0, 0, 0);
    a11 = __builtin_amdgcn_mfma_f32_16x16x32_bf16(bh1, xl1, a11, 0, 0, 0);

    // t=0: dist[p] = 8 in-lane z^2 + reduce over g via shfl_xor(16,32)
    {
      float u = fmaf(a00[0], a00[0], a00[1] * a00[1]);
      u = fmaf(a00[2], a00[2], u);
      u = fmaf(a00[3], a00[3], u);
      float v = fmaf(a01[0], a01[0], a01[1] * a01[1]);
      v = fmaf(a01[2], a01[2], v);
      v = fmaf(a01[3], a01[3], v);
      float s = u + v;
      s += __shfl_xor(s, 16);
      s += __shfl_xor(s, 32);
      result0 += exp2f(lc - s);
    }
    // t=1
    {
      float u = fmaf(a10[0], a10[0], a10[1] * a10[1]);
      u = fmaf(a10[2], a10[2], u);
      u = fmaf(a10[3], a10[3], u);
      float v = fmaf(a11[0], a11[0], a11[1] * a11[1]);
      v = fmaf(a11[2], a11[2], v);
      v = fmaf(a11[3], a11[3], v);
      float s = u + v;
      s += __shfl_xor(s, 16);
      s += __shfl_xor(s, 32);
      result1 += exp2f(lc - s);
    }
  }

  // all lanes hold full sums; lanes 0..15 write 16 contiguous floats per tile
  if (lane < 16) {
    out[tileBase + col] = result0;
    out[tileBase + 16 + col] = result1;
  }
}

extern "C" void kernel_launch(void* const* d_in, const int* in_sizes, int n_in,
                              void* d_out, int out_size, void* d_ws, size_t ws_size,
                              hipStream_t stream) {
  const float* points  = (const float*)d_in[0];
  const float* centers = (const float*)d_in[1];
  const float* L       = (const float*)d_in[2];
  const float* weights = (const float*)d_in[3];
  float* out = (float*)d_out;
  const int N = in_sizes[0] / D;

  char* ws = (char*)d_ws;
  float* CNf          = (float*)ws;                     // 32*32*4 = 4096 B
  float* LC           = (float*)(ws + 4096);            // 128 B
  unsigned short* LHf = (unsigned short*)(ws + 8192);   // 65536 B
  unsigned short* LLf = (unsigned short*)(ws + 8192 + 65536);

  gmm_pre<<<M, 64, 0, stream>>>(centers, L, weights, CNf, LC, LHf, LLf);

  // 1024 threads = 16 waves; 512 points per block; grid = 256 = 1 block/CU
  gmm_main<<<N / (16 * WT * 16), 1024, 0, stream>>>(
      points, CNf, LC, LHf, LLf, out, N);
}